// Round 1
// 5868.433 us; speedup vs baseline: 1.0896x; 1.0896x over previous
//
#include <hip/hip_runtime.h>
#include <math.h>

#define BB 2048
#define DD 512
#define CC 128
#define TT 151
#define G3 1536  // 3*D

typedef __bf16 bf16x8 __attribute__((ext_vector_type(8)));
typedef float f32x4 __attribute__((ext_vector_type(4)));

// ---------------- precompute kernels ----------------

// WihT[k*G3 + j] = Wih[j*DD + k]  (for E build)
__global__ void k_transpose_wih(const float* __restrict__ Wih, float* __restrict__ WihT) {
    int idx = blockIdx.x * 256 + threadIdx.x;
    if (idx < G3 * DD) {
        int j = idx / DD, k = idx - j * DD;
        WihT[k * G3 + j] = Wih[idx];
    }
}

// Pack W_proj into split-bf16 MFMA B-fragments, one 16-col tile per wave.
// out[w*16384 + kt*1024 + part*512 + lane*8 + j]:
//   c = w*16 + (lane&15), k = kt*32 + (lane>>4)*8 + j, part 0=hi 1=lo
__global__ void k_pack_wp_frag(const float* __restrict__ Wproj, __bf16* __restrict__ out) {
    int idx = blockIdx.x * 256 + threadIdx.x;  // 131072
    if (idx >= 131072) return;
    int j = idx & 7;
    int lane = (idx >> 3) & 63;
    int part = (idx >> 9) & 1;
    int kt = (idx >> 10) & 15;
    int w = idx >> 14;
    int c = w * 16 + (lane & 15);
    int k = kt * 32 + (lane >> 4) * 8 + j;
    float v = Wproj[c * DD + k];
    __bf16 hi = (__bf16)v;
    out[idx] = part ? (__bf16)(v - (float)hi) : hi;
}

// Pack W_hh into split-bf16 B-fragments in per-wave streaming order. (unchanged)
// Layout: [w 0..7][kt 0..15][tile 0..11][part hi/lo][lane 0..63][j 0..7]  (bf16)
__global__ void k_pack_whh_frag(const float* __restrict__ Whh, __bf16* __restrict__ out) {
    int idx = blockIdx.x * 256 + threadIdx.x;  // 786432
    if (idx >= 786432) return;
    int j8 = idx & 7;
    int lane = (idx >> 3) & 63;
    int rest = idx >> 9;          // tile + 12*(kt + 16*w)
    int tile = rest % 12;
    int kt = (rest / 12) % 16;
    int w = rest / (12 * 16);
    int g = tile >> 2, tl = tile & 3;
    int colc = lane & 15, quad = lane >> 4;
    int jcol = g * 512 + w * 64 + tl * 16 + colc;
    int k = kt * 32 + quad * 8 + j8;
    float v = Whh[jcol * DD + k];
    __bf16 hi = (__bf16)v;
    __bf16 lo = (__bf16)(v - (float)hi);
    size_t base = ((((size_t)w * 16 + kt) * 12 + tile) * 2) * 512 + lane * 8 + j8;
    out[base] = hi;
    out[base + 512] = lo;
}

// E[c][j] = b_ih[j] + (j<1024 ? b_hh[j] : 0) + sum_k embed[c][k]*W_ih[j][k]; row 128 = biases only
__global__ void k_build_E(const float* __restrict__ embed, const float* __restrict__ WihT,
                          const float* __restrict__ b_ih, const float* __restrict__ b_hh,
                          float* __restrict__ E) {
    __shared__ float emb[16][DD];
    const int t = threadIdx.x;
    const int j = blockIdx.x * 256 + t;
    const int c0 = blockIdx.y * 16;
    for (int i = 0; i < 16; i++) {
        int c = c0 + i;
        for (int k = t; k < DD; k += 256)
            emb[i][k] = (c < CC) ? embed[c * DD + k] : 0.0f;
    }
    __syncthreads();
    float acc[16];
#pragma unroll
    for (int i = 0; i < 16; i++) acc[i] = 0.0f;
    for (int k = 0; k < DD; k++) {
        float wv = WihT[k * G3 + j];
#pragma unroll
        for (int i = 0; i < 16; i++) acc[i] = fmaf(emb[i][k], wv, acc[i]);
    }
    float bj = b_ih[j] + (j < 1024 ? b_hh[j] : 0.0f);
    for (int i = 0; i < 16; i++) {
        int c = c0 + i;
        if (c <= CC) E[(size_t)c * G3 + j] = acc[i] + bj;
    }
}

// ---------------- main persistent GRU kernel ----------------

__device__ __forceinline__ float fast_sigmoid(float x) {
    return __builtin_amdgcn_rcpf(1.0f + __expf(-x));
}
__device__ __forceinline__ float fast_tanh(float x) {
    x = fminf(10.0f, fmaxf(-10.0f, x));
    float e = __expf(2.0f * x);
    return (e - 1.0f) * __builtin_amdgcn_rcpf(e + 1.0f);
}

// 16 real rows per block (M=16 fully used), grid = 128.
// Weight traffic per step halves vs 8-row version; projection moved to MFMA.
__global__ __launch_bounds__(512, 2) void k_gru(
    const float* __restrict__ feat, const __bf16* __restrict__ Whf,
    const __bf16* __restrict__ Wpf, const float* __restrict__ b_proj,
    const float* __restrict__ b_hh, const float* __restrict__ Ep,
    float* __restrict__ out) {
    __shared__ __align__(16) __bf16 h_hi[16][520];  // 16.25 KB, +8 col pad (bank spread)
    __shared__ __align__(16) __bf16 h_lo[16][520];  // 16.25 KB
    __shared__ float lgbuf[16][CC][9];              // 72 KB logit burst buffer (+1 pad)
    __shared__ int tok_s[16];

    float* out_logits = out;                      // [B][C][T]
    float* out_tok = out + (size_t)BB * CC * TT;  // [B][T] as float

    const int t = threadIdx.x;   // 0..511
    const int w = t >> 6;        // wave 0..7: owns gh cols [64w,64w+64) per gate
    const int lane = t & 63;
    const int row0 = blockIdx.x * 16;
    const int col = lane & 15;   // MFMA A-row / D-col index
    const int quad = lane >> 4;
    const int bq = quad * 4;     // D-frag base row

    // ---- init: h0 = feat -> registers (h_old) + split-bf16 LDS
    float ho[4][4];  // [tile][rg] : h_old for (b=bq+rg, d=w*64+tile*16+col)
#pragma unroll
    for (int tile = 0; tile < 4; tile++) {
        const int d = w * 64 + tile * 16 + col;
#pragma unroll
        for (int rg = 0; rg < 4; rg++) {
            const int b = bq + rg;
            float v = feat[(size_t)(row0 + b) * DD + d];
            ho[tile][rg] = v;
            __bf16 hi = (__bf16)v;
            h_hi[b][d] = hi;
            h_lo[b][d] = (__bf16)(v - (float)hi);
        }
    }
    if (t < 16) tok_s[t] = CC;  // start token -> E row 128 (x0 = 0)

    // per-lane constants
    const float bp = b_proj[w * 16 + col];
    float bhn_t[4];
#pragma unroll
    for (int tile = 0; tile < 4; tile++)
        bhn_t[tile] = b_hh[1024 + w * 64 + tile * 16 + col];

    const __bf16* wseq = Whf + (size_t)w * 196608;  // per-wave W_hh stream
    const __bf16* wpseq = Wpf + (size_t)w * 16384;  // per-wave W_proj stream
    __syncthreads();

    for (int step = 0; step < TT; step++) {
        const int sl = step & 7;

        // ---- P1: gh = h @ W_hh^T via split-bf16 MFMA, M=16 all-real
        f32x4 acc[12];
#pragma unroll
        for (int i = 0; i < 12; i++) acc[i] = (f32x4)(0.0f);
        for (int kt = 0; kt < 16; kt++) {
            bf16x8 ahi = *(const bf16x8*)&h_hi[col][kt * 32 + quad * 8];
            bf16x8 alo = *(const bf16x8*)&h_lo[col][kt * 32 + quad * 8];
            const __bf16* wk = wseq + kt * 12288;
#pragma unroll
            for (int tile = 0; tile < 12; tile++) {
                bf16x8 bhi = *(const bf16x8*)(wk + tile * 1024 + lane * 8);
                bf16x8 blo = *(const bf16x8*)(wk + tile * 1024 + 512 + lane * 8);
                acc[tile] = __builtin_amdgcn_mfma_f32_16x16x32_bf16(ahi, bhi, acc[tile], 0, 0, 0);
                acc[tile] = __builtin_amdgcn_mfma_f32_16x16x32_bf16(alo, bhi, acc[tile], 0, 0, 0);
                acc[tile] = __builtin_amdgcn_mfma_f32_16x16x32_bf16(ahi, blo, acc[tile], 0, 0, 0);
            }
        }
        __syncthreads();  // all waves done reading h_hi/h_lo

        // ---- P2: gates in registers; D-frag (row=bq+rg, col=w*64+tile*16+col)
        {
            int tk[4];
#pragma unroll
            for (int rg = 0; rg < 4; rg++) tk[rg] = tok_s[bq + rg];
#pragma unroll
            for (int tile = 0; tile < 4; tile++) {
                const int d = w * 64 + tile * 16 + col;
#pragma unroll
                for (int rg = 0; rg < 4; rg++) {
                    const int b = bq + rg;
                    const float* Er = Ep + (size_t)tk[rg] * G3 + d;
                    float rr = fast_sigmoid(acc[tile][rg] + Er[0]);        // E has b_ih+b_hh(r)
                    float zz = fast_sigmoid(acc[4 + tile][rg] + Er[512]);  // E has b_ih+b_hh(z)
                    float nn = fast_tanh(Er[1024] + rr * (acc[8 + tile][rg] + bhn_t[tile]));
                    float hv = (1.0f - zz) * nn + zz * ho[tile][rg];
                    ho[tile][rg] = hv;
                    __bf16 hi = (__bf16)hv;
                    h_hi[b][d] = hi;
                    h_lo[b][d] = (__bf16)(hv - (float)hi);
                }
            }
        }
        __syncthreads();  // h_new visible

        // ---- P3a: logits via split-bf16 MFMA; wave w -> cols [16w,16w+16)
        {
            f32x4 accp = (f32x4)(0.0f);
            for (int kt = 0; kt < 16; kt++) {
                bf16x8 ahi = *(const bf16x8*)&h_hi[col][kt * 32 + quad * 8];
                bf16x8 alo = *(const bf16x8*)&h_lo[col][kt * 32 + quad * 8];
                const __bf16* pk = wpseq + kt * 1024;
                bf16x8 bhi = *(const bf16x8*)(pk + lane * 8);
                bf16x8 blo = *(const bf16x8*)(pk + 512 + lane * 8);
                accp = __builtin_amdgcn_mfma_f32_16x16x32_bf16(ahi, bhi, accp, 0, 0, 0);
                accp = __builtin_amdgcn_mfma_f32_16x16x32_bf16(alo, bhi, accp, 0, 0, 0);
                accp = __builtin_amdgcn_mfma_f32_16x16x32_bf16(ahi, blo, accp, 0, 0, 0);
            }
#pragma unroll
            for (int rg = 0; rg < 4; rg++)
                lgbuf[bq + rg][w * 16 + col][sl] = accp[rg] + bp;
        }
        __syncthreads();  // full logit rows visible

        // ---- P3b: argmax; wave w handles rows 2w, 2w+1
        {
#pragma unroll
            for (int pass = 0; pass < 2; pass++) {
                const int r = w * 2 + pass;
                float v0 = lgbuf[r][lane][sl];
                float v1 = lgbuf[r][lane + 64][sl];
                float bv; int bi;
                if (v0 >= v1) { bv = v0; bi = lane; } else { bv = v1; bi = lane + 64; }
#pragma unroll
                for (int off = 32; off > 0; off >>= 1) {
                    float ov = __shfl_down(bv, off, 64);
                    int oi = __shfl_down(bi, off, 64);
                    if (ov > bv || (ov == bv && oi < bi)) { bv = ov; bi = oi; }
                }
                if (lane == 0) {
                    tok_s[r] = bi;
                    __builtin_nontemporal_store((float)bi, &out_tok[(size_t)(row0 + r) * TT + step]);
                }
            }
        }
        __syncthreads();  // tok_s visible for next P2; lgbuf stable for flush

        // ---- flush logits every 8 steps (nontemporal: keep weights L2-resident)
        if ((step & 7) == 7 || step == TT - 1) {
            const int t0 = step & ~7;
            const int cnt = step - t0 + 1;
#pragma unroll
            for (int p = 0; p < 4; p++) {
                const int pair = t + p * 512;          // 0..2047
                const int b = pair >> 7, c = pair & (CC - 1);
                float* dst = out_logits + ((size_t)(row0 + b) * CC + c) * TT + t0;
                const float* src = &lgbuf[b][c][0];
                for (int s = 0; s < cnt; s++) __builtin_nontemporal_store(src[s], &dst[s]);
            }
        }
    }
}

// ---------------- launcher ----------------

extern "C" void kernel_launch(void* const* d_in, const int* in_sizes, int n_in,
                              void* d_out, int out_size, void* d_ws, size_t ws_size,
                              hipStream_t stream) {
    const float* feat   = (const float*)d_in[0];
    const float* W_ih   = (const float*)d_in[1];
    const float* W_hh   = (const float*)d_in[2];
    const float* b_ih   = (const float*)d_in[3];
    const float* b_hh   = (const float*)d_in[4];
    const float* W_proj = (const float*)d_in[5];
    const float* b_proj = (const float*)d_in[6];
    const float* embed  = (const float*)d_in[7];
    float* out = (float*)d_out;

    float* ws = (float*)d_ws;
    float*  WihT = ws;                         // 786432 floats
    float*  E    = ws + 786432;                // 198144 floats
    __bf16* Wpf  = (__bf16*)(ws + 984576);     // 131072 bf16 = 65536 float slots
    __bf16* Whf  = (__bf16*)(ws + 1050112);    // 1572864 bf16 = 786432 float slots
    // total: 1836544 floats = 7.3 MB

    hipLaunchKernelGGL(k_transpose_wih, dim3(3072), dim3(256), 0, stream, W_ih, WihT);
    hipLaunchKernelGGL(k_pack_wp_frag, dim3(512), dim3(256), 0, stream, W_proj, Wpf);
    hipLaunchKernelGGL(k_pack_whh_frag, dim3(3072), dim3(256), 0, stream, W_hh, Whf);
    hipLaunchKernelGGL(k_build_E, dim3(6, 9), dim3(256), 0, stream, embed, WihT, b_ih, b_hh, E);
    hipLaunchKernelGGL(k_gru, dim3(128), dim3(512), 0, stream,
                       feat, Whf, Wpf, b_proj, b_hh, E, out);
}